// Round 10
// baseline (144.392 us; speedup 1.0000x reference)
//
#include <hip/hip_runtime.h>
#include <hip/hip_bf16.h>

#define EMBED 128   // node embedding dim
#define HID   64    // hidden dim

typedef unsigned short ushort;
typedef ushort ushort8 __attribute__((ext_vector_type(8)));
typedef ushort ushort4_t __attribute__((ext_vector_type(4)));
typedef short  bf16x8  __attribute__((ext_vector_type(8)));   // 8 bf16 = 4 VGPR
typedef float  f32x4   __attribute__((ext_vector_type(4)));

__device__ __forceinline__ float bf2f(ushort u) {
    union { unsigned int i; float f; } c;
    c.i = ((unsigned int)u) << 16;
    return c.f;
}
__device__ __forceinline__ ushort f2bf(float f) {
    union { float f; unsigned int i; } c;
    c.f = f;
    unsigned int r = c.i + 0x7FFFu + ((c.i >> 16) & 1u);   // RTNE
    return (ushort)(r >> 16);
}

// ---------------------------------------------------------------------------
// frag_prep: write B2 = [W1-src-half | W1-dst-half] as MFMA fragments in
// exact per-lane order, split hi/lo bf16 (compensated: hi+lo ~= fp32).
// Frag (jt,kt): lane l, reg r holds B2[k = kt*32 + 8*(l>>4) + r][jt*16 + (l&15)].
// (Same lane layout serves as A- or B-operand; round-9 pass verified it.)
// ---------------------------------------------------------------------------
__global__ __launch_bounds__(256)
void frag_prep_kernel(const float* __restrict__ W1, ushort* __restrict__ fragH,
                      ushort* __restrict__ fragL) {
    const int tid = blockIdx.x * 256 + threadIdx.x;
    if (tid >= 2048) return;
    const int lane = tid & 63;
    const int kt   = (tid >> 6) & 3;
    const int jt   = tid >> 8;          // 0..7
    const int q    = lane >> 4;
    const int m16  = lane & 15;

    ushort8 fh, fl;
#pragma unroll
    for (int r = 0; r < 8; ++r) {
        const int k = kt * 32 + q * 8 + r;
        const int j = jt * 16 + m16;
        const float v = (j < HID) ? W1[k * HID + j]
                                  : W1[(EMBED + k) * HID + (j - HID)];
        const ushort h = f2bf(v);
        fh[r] = h;
        fl[r] = f2bf(v - bf2f(h));
    }
    const int fi = (jt * 4 + kt) * 64 + lane;
    *(ushort8*)(fragH + fi * 8) = fh;
    *(ushort8*)(fragL + fi * 8) = fl;
}

// ---------------------------------------------------------------------------
// node_proj_mfma: P[n][jj] = (Z[n] @ B2)[jj] + 0.5*b1[jj&63], stored bf16.
// Split-bf16 MFMA, OPERAND-SWAPPED: acc = mfma(W, Z) -> D^T so that
//   D col = node = lane&15, D row = j = (lane>>4)*4 + reg.
// Each lane owns node n0+(l&15) x 4 consecutive j per jt -> 8B ushort4
// stores (16 stores/thread vs 128 scalar 2B stores before).
// Block 256 = 4 waves; wave owns 32 nodes (two 16-node tiles) x 128 j.
// LDS: frags hi+lo 64 KB -> 2 blocks/CU. Z loads: 16 rows x 128B per kt,
// each L2 line touched exactly once.
// ---------------------------------------------------------------------------
__global__ __launch_bounds__(256, 2)
void node_proj_mfma(const float* __restrict__ Z, const ushort* __restrict__ fragH,
                    const ushort* __restrict__ fragL, const float* __restrict__ b1,
                    ushort* __restrict__ P, int n_nodes) {
    __shared__ __align__(16) ushort sFH[32 * 64 * 8];   // 32 KB
    __shared__ __align__(16) ushort sFL[32 * 64 * 8];   // 32 KB

    const int t = threadIdx.x;

    // stage frags (coalesced 16B copies; L2-hot after first blocks)
    for (int i = t; i < 2048; i += 256) {
        ((ushort8*)sFH)[i] = ((const ushort8*)fragH)[i];
        ((ushort8*)sFL)[i] = ((const ushort8*)fragL)[i];
    }

    const int wave = t >> 6;
    const int lane = t & 63;
    const int q    = lane >> 4;       // k-group / j-subgroup
    const int m16  = lane & 15;       // node-within-tile
    const int n0   = blockIdx.x * 128 + wave * 32;

    const int rA = n0 + m16;
    const int rB = n0 + 16 + m16;
    const float* gA = Z + (size_t)(rA < n_nodes ? rA : n_nodes - 1) * EMBED;
    const float* gB = Z + (size_t)(rB < n_nodes ? rB : n_nodes - 1) * EMBED;

    // bias per lane: j = jt*16 + q*4 + r -> j&63 = (jt&3)*16 + q*4 + r
    float4 bb[4];
#pragma unroll
    for (int jm = 0; jm < 4; ++jm) {
        const float4 bv = *(const float4*)(b1 + jm * 16 + q * 4);
        bb[jm].x = 0.5f * bv.x; bb[jm].y = 0.5f * bv.y;
        bb[jm].z = 0.5f * bv.z; bb[jm].w = 0.5f * bv.w;
    }

    __syncthreads();

    f32x4 acc0[8], acc1[8];
#pragma unroll
    for (int jt = 0; jt < 8; ++jt) {
        acc0[jt] = (f32x4){0.f, 0.f, 0.f, 0.f};
        acc1[jt] = (f32x4){0.f, 0.f, 0.f, 0.f};
    }

    for (int kt = 0; kt < 4; ++kt) {
        const int k0 = kt * 32 + q * 8;

        float za[8], zb[8];
        *(float4*)(za)     = *(const float4*)(gA + k0);
        *(float4*)(za + 4) = *(const float4*)(gA + k0 + 4);
        *(float4*)(zb)     = *(const float4*)(gB + k0);
        *(float4*)(zb + 4) = *(const float4*)(gB + k0 + 4);

        bf16x8 ah0, al0, ah1, al1;
#pragma unroll
        for (int r = 0; r < 8; ++r) {
            const ushort h0 = f2bf(za[r]);
            ah0[r] = (short)h0;
            al0[r] = (short)f2bf(za[r] - bf2f(h0));
            const ushort h1 = f2bf(zb[r]);
            ah1[r] = (short)h1;
            al1[r] = (short)f2bf(zb[r] - bf2f(h1));
        }

#pragma unroll
        for (int jt = 0; jt < 8; ++jt) {
            const int fi = (jt * 4 + kt) * 64 + lane;
            const bf16x8 bh = ((const bf16x8*)sFH)[fi];
            const bf16x8 bl = ((const bf16x8*)sFL)[fi];

            // W as A-operand, Z as B-operand -> D^T (node = col = lane&15)
            acc0[jt] = __builtin_amdgcn_mfma_f32_16x16x32_bf16(bh, ah0, acc0[jt], 0, 0, 0);
            acc0[jt] = __builtin_amdgcn_mfma_f32_16x16x32_bf16(bh, al0, acc0[jt], 0, 0, 0);
            acc0[jt] = __builtin_amdgcn_mfma_f32_16x16x32_bf16(bl, ah0, acc0[jt], 0, 0, 0);

            acc1[jt] = __builtin_amdgcn_mfma_f32_16x16x32_bf16(bh, ah1, acc1[jt], 0, 0, 0);
            acc1[jt] = __builtin_amdgcn_mfma_f32_16x16x32_bf16(bh, al1, acc1[jt], 0, 0, 0);
            acc1[jt] = __builtin_amdgcn_mfma_f32_16x16x32_bf16(bl, ah1, acc1[jt], 0, 0, 0);
        }
    }

    // epilogue: lane owns node rA (and rB), j = jt*16 + q*4 + {0..3}
    if (rA < n_nodes) {
        ushort* pr = P + (size_t)rA * 128 + q * 4;
#pragma unroll
        for (int jt = 0; jt < 8; ++jt) {
            const float4 bv = bb[jt & 3];
            ushort4_t pk;
            pk[0] = f2bf(acc0[jt][0] + bv.x);
            pk[1] = f2bf(acc0[jt][1] + bv.y);
            pk[2] = f2bf(acc0[jt][2] + bv.z);
            pk[3] = f2bf(acc0[jt][3] + bv.w);
            *(ushort4_t*)(pr + jt * 16) = pk;
        }
    }
    if (rB < n_nodes) {
        ushort* pr = P + (size_t)rB * 128 + q * 4;
#pragma unroll
        for (int jt = 0; jt < 8; ++jt) {
            const float4 bv = bb[jt & 3];
            ushort4_t pk;
            pk[0] = f2bf(acc1[jt][0] + bv.x);
            pk[1] = f2bf(acc1[jt][1] + bv.y);
            pk[2] = f2bf(acc1[jt][2] + bv.z);
            pk[3] = f2bf(acc1[jt][3] + bv.w);
            *(ushort4_t*)(pr + jt * 16) = pk;
        }
    }
}

// ---------------------------------------------------------------------------
// Kernel 2: per-edge MLP over bf16 P, b1 pre-folded. 8 lanes/edge; lane l
// owns h[8l:8l+8]: one 16B bf16x8 gather per side. shfl_xor tree over 8.
//   out[e] = b2 + sum_j relu(P[s][j] + P[d][64+j]) * W2[j]
// ---------------------------------------------------------------------------
__global__ __launch_bounds__(256)
void edge_mlp_kernel(const ushort* __restrict__ P, const int* __restrict__ src,
                     const int* __restrict__ dst, const float* __restrict__ W2,
                     const float* __restrict__ b2, float* __restrict__ out,
                     int n_edges) {
    const int gtid  = blockIdx.x * 256 + threadIdx.x;
    const int lane8 = gtid & 7;
    const int e     = gtid >> 3;
    if (e >= n_edges) return;

    const float4 w2a = *(const float4*)(W2 + lane8 * 8);
    const float4 w2b = *(const float4*)(W2 + lane8 * 8 + 4);

    const int s = src[e];
    const int d = dst[e];
    const ushort8 ps = *(const ushort8*)(P + (size_t)s * 128 + lane8 * 8);
    const ushort8 pd = *(const ushort8*)(P + (size_t)d * 128 + HID + lane8 * 8);

    float part;
    {
        const float h0 = fmaxf(bf2f(ps[0]) + bf2f(pd[0]), 0.f);
        const float h1 = fmaxf(bf2f(ps[1]) + bf2f(pd[1]), 0.f);
        const float h2 = fmaxf(bf2f(ps[2]) + bf2f(pd[2]), 0.f);
        const float h3 = fmaxf(bf2f(ps[3]) + bf2f(pd[3]), 0.f);
        const float h4 = fmaxf(bf2f(ps[4]) + bf2f(pd[4]), 0.f);
        const float h5 = fmaxf(bf2f(ps[5]) + bf2f(pd[5]), 0.f);
        const float h6 = fmaxf(bf2f(ps[6]) + bf2f(pd[6]), 0.f);
        const float h7 = fmaxf(bf2f(ps[7]) + bf2f(pd[7]), 0.f);
        part = h0 * w2a.x + h1 * w2a.y + h2 * w2a.z + h3 * w2a.w
             + h4 * w2b.x + h5 * w2b.y + h6 * w2b.z + h7 * w2b.w;
    }

    part += __shfl_xor(part, 4, 8);
    part += __shfl_xor(part, 2, 8);
    part += __shfl_xor(part, 1, 8);

    if (lane8 == 0) out[e] = part + b2[0];
}

// ---------------------------------------------------------------------------
// FALLBACK (ws too small): workspace-free direct per-edge MLP, W1 in LDS.
// ---------------------------------------------------------------------------
__global__ __launch_bounds__(256)
void edge_direct_kernel(const float* __restrict__ Z, const int* __restrict__ src,
                        const int* __restrict__ dst, const float* __restrict__ W1,
                        const float* __restrict__ b1, const float* __restrict__ W2,
                        const float* __restrict__ b2, float* __restrict__ out,
                        int n_edges) {
    __shared__ float w1s[2 * EMBED * HID];   // 64 KB
    for (int i = threadIdx.x; i < 2 * EMBED * HID; i += 256) w1s[i] = W1[i];
    __syncthreads();

    const int gtid   = blockIdx.x * 256 + threadIdx.x;
    const int lane16 = gtid & 15;
    const int e      = gtid >> 4;
    if (e >= n_edges) return;

    const int s = src[e];
    const int d = dst[e];
    const float* zs = Z + (size_t)s * EMBED;
    const float* zd = Z + (size_t)d * EMBED;

    float h[4] = {b1[lane16 * 4 + 0], b1[lane16 * 4 + 1],
                  b1[lane16 * 4 + 2], b1[lane16 * 4 + 3]};
    for (int k = 0; k < EMBED; ++k) {
        const float zsk = zs[k];
        const float zdk = zd[k];
        const float4 w1a = *(const float4*)(&w1s[k * HID + lane16 * 4]);
        const float4 w1b = *(const float4*)(&w1s[(EMBED + k) * HID + lane16 * 4]);
        h[0] = fmaf(zsk, w1a.x, fmaf(zdk, w1b.x, h[0]));
        h[1] = fmaf(zsk, w1a.y, fmaf(zdk, w1b.y, h[1]));
        h[2] = fmaf(zsk, w1a.z, fmaf(zdk, w1b.z, h[2]));
        h[3] = fmaf(zsk, w1a.w, fmaf(zdk, w1b.w, h[3]));
    }

    const float4 w2v = *(const float4*)(W2 + lane16 * 4);
    float part = fmaxf(h[0], 0.f) * w2v.x + fmaxf(h[1], 0.f) * w2v.y +
                 fmaxf(h[2], 0.f) * w2v.z + fmaxf(h[3], 0.f) * w2v.w;
    part += __shfl_xor(part, 8, 16);
    part += __shfl_xor(part, 4, 16);
    part += __shfl_xor(part, 2, 16);
    part += __shfl_xor(part, 1, 16);

    if (lane16 == 0) out[e] = part + b2[0];
}

extern "C" void kernel_launch(void* const* d_in, const int* in_sizes, int n_in,
                              void* d_out, int out_size, void* d_ws, size_t ws_size,
                              hipStream_t stream) {
    const float* Z  = (const float*)d_in[0];
    const int*   EI = (const int*)d_in[1];   // [2, E]: src row then dst row
    const float* W1 = (const float*)d_in[2]; // [256, 64] row-major
    const float* b1 = (const float*)d_in[3]; // [64]
    const float* W2 = (const float*)d_in[4]; // [64]
    const float* b2 = (const float*)d_in[5]; // [1]
    float* out = (float*)d_out;

    const int n_nodes = in_sizes[0] / EMBED;
    const int E       = in_sizes[1] / 2;

    const size_t p_bytes    = (size_t)n_nodes * (2 * HID) * sizeof(ushort); // 25.6 MB
    const size_t frag_bytes = 32 * 64 * 8 * sizeof(ushort);                 // 32 KB each

    if (ws_size >= p_bytes + 2 * frag_bytes) {
        ushort* P     = (ushort*)d_ws;
        ushort* fragH = (ushort*)((char*)d_ws + p_bytes);
        ushort* fragL = (ushort*)((char*)d_ws + p_bytes + frag_bytes);

        frag_prep_kernel<<<8, 256, 0, stream>>>(W1, fragH, fragL);

        const int node_blocks = (n_nodes + 127) / 128;
        node_proj_mfma<<<node_blocks, 256, 0, stream>>>(Z, fragH, fragL, b1, P, n_nodes);

        const int edge_blocks = (E * 8 + 255) / 256;
        edge_mlp_kernel<<<edge_blocks, 256, 0, stream>>>(
            P, EI, EI + E, W2, b2, out, E);
    } else {
        const int edge_blocks = (E * 16 + 255) / 256;
        edge_direct_kernel<<<edge_blocks, 256, 0, stream>>>(
            Z, EI, EI + E, W1, b1, W2, b2, out, E);
    }
}